// Round 1
// baseline (56539.691 us; speedup 1.0000x reference)
//
#include <hip/hip_runtime.h>
#include <math.h>

// Problem constants (match reference)
#define BATCH  32
#define T_IN   256
#define T_OUT  256
#define DIM    128   // D
#define UNITS  256   // U
#define G3     768   // 3*U
#define NSTEPS (T_IN + T_OUT - 1)   // 511 total timesteps

__device__ __forceinline__ float sigmoidf_(float x) {
    return 1.0f / (1.0f + __expf(-x));
}

// One workgroup per batch element. 768 threads: thread j owns gate column j.
// All state lives in LDS; weights stream from L2/LLC each step.
__global__ __launch_bounds__(G3) void gru_ar_kernel(
    const float* __restrict__ inputs,  // [B, T_IN, D]
    const float* __restrict__ noise,   // [B, T_IN, D]
    const float* __restrict__ h_init,  // [3, U]
    const float* __restrict__ W0,      // [D, 3U]
    const float* __restrict__ U0,      // [U, 3U]
    const float* __restrict__ b0,      // [2, 3U]
    const float* __restrict__ W1,      // [U, 3U]
    const float* __restrict__ U1,      // [U, 3U]
    const float* __restrict__ b1,      // [2, 3U]
    const float* __restrict__ W2,      // [U, 3U]
    const float* __restrict__ U2,      // [U, 3U]
    const float* __restrict__ b2,      // [2, 3U]
    const float* __restrict__ Wd,      // [U, D]
    const float* __restrict__ bd,      // [D]
    float* __restrict__ out)           // [B, T_OUT, D]
{
    const int b = blockIdx.x;
    const int j = threadIdx.x;

    __shared__ float s_x[UNITS];        // current layer input (D or U wide)
    __shared__ float s_h[3][UNITS];     // recurrent states
    __shared__ float s_gz[UNITS];       // z pre-activation (gx+gh)
    __shared__ float s_gr[UNITS];       // r pre-activation (gx+gh)
    __shared__ float s_gxn[UNITS];      // n input part
    __shared__ float s_ghn[UNITS];      // n recurrent part (r multiplies this)
    __shared__ float s_pred[DIM];       // AR feedback

    // init states: tiled learnable vectors (identical across batch)
    if (j < UNITS) {
        s_h[0][j] = h_init[0 * UNITS + j];
        s_h[1][j] = h_init[1 * UNITS + j];
        s_h[2][j] = h_init[2 * UNITS + j];
    }
    __syncthreads();

    const float* Ws[3]  = {W0, W1, W2};
    const float* Us[3]  = {U0, U1, U2};
    const float* bss[3] = {b0, b1, b2};

    for (int t = 0; t < NSTEPS; ++t) {
        // ---- load step input into s_x[0..D) ----
        if (j < DIM) {
            if (t < T_IN) {
                const int idx = (b * T_IN + t) * DIM + j;
                s_x[j] = inputs[idx] + noise[idx];   // noise only in warmup
            } else {
                s_x[j] = s_pred[j];                  // AR feedback
            }
        }
        __syncthreads();

        // ---- 3 GRU cells ----
        #pragma unroll
        for (int l = 0; l < 3; ++l) {
            const int K = (l == 0) ? DIM : UNITS;
            const float* __restrict__ W    = Ws[l];
            const float* __restrict__ Urec = Us[l];
            const float* __restrict__ bias = bss[l];

            // gate pre-activations for column j
            float gx = bias[j];
            #pragma unroll 4
            for (int k = 0; k < K; ++k)
                gx = fmaf(s_x[k], W[k * G3 + j], gx);

            float gh = bias[G3 + j];
            #pragma unroll 4
            for (int k = 0; k < UNITS; ++k)
                gh = fmaf(s_h[l][k], Urec[k * G3 + j], gh);

            if (j < UNITS)            s_gz[j] = gx + gh;
            else if (j < 2 * UNITS)   s_gr[j - UNITS] = gx + gh;
            else { s_gxn[j - 2 * UNITS] = gx; s_ghn[j - 2 * UNITS] = gh; }
            __syncthreads();

            // cell update + residual (threads 0..U-1)
            if (j < UNITS) {
                const float z = sigmoidf_(s_gz[j]);
                const float r = sigmoidf_(s_gr[j]);
                const float n = tanhf(s_gxn[j] + r * s_ghn[j]);
                const float h_old = s_h[l][j];
                const float h_new = z * h_old + (1.0f - z) * n;
                s_h[l][j] = h_new;
                // layer 0: x = h ; layers 1,2: x = h + x (residual)
                s_x[j] = (l == 0) ? h_new : (h_new + s_x[j]);
            }
            __syncthreads();
        }

        // ---- dense readout (pred) once warmup ends ----
        if (t >= T_IN - 1) {
            if (j < DIM) {
                float p = bd[j];
                #pragma unroll 4
                for (int k = 0; k < UNITS; ++k)
                    p = fmaf(s_x[k], Wd[k * DIM + j], p);
                s_pred[j] = p;
                out[(b * T_OUT + (t - (T_IN - 1))) * DIM + j] = p;
            }
            __syncthreads();
        }
    }
}

extern "C" void kernel_launch(void* const* d_in, const int* in_sizes, int n_in,
                              void* d_out, int out_size, void* d_ws, size_t ws_size,
                              hipStream_t stream) {
    const float* inputs = (const float*)d_in[0];
    const float* noise  = (const float*)d_in[1];
    const float* h_init = (const float*)d_in[2];
    const float* W0 = (const float*)d_in[3];
    const float* U0 = (const float*)d_in[4];
    const float* b0 = (const float*)d_in[5];
    const float* W1 = (const float*)d_in[6];
    const float* U1 = (const float*)d_in[7];
    const float* b1 = (const float*)d_in[8];
    const float* W2 = (const float*)d_in[9];
    const float* U2 = (const float*)d_in[10];
    const float* b2 = (const float*)d_in[11];
    const float* Wd = (const float*)d_in[12];
    const float* bd = (const float*)d_in[13];
    float* out = (float*)d_out;

    gru_ar_kernel<<<BATCH, G3, 0, stream>>>(
        inputs, noise, h_init, W0, U0, b0, W1, U1, b1, W2, U2, b2, Wd, bd, out);
}

// Round 2
// 8917.803 us; speedup vs baseline: 6.3401x; 6.3401x over previous
//
#include <hip/hip_runtime.h>
#include <math.h>

// Problem constants (match reference)
#define BATCH  32
#define T_IN   256
#define T_OUT  256
#define DIM    128   // D
#define UNITS  256   // U
#define G3     768   // 3*U
#define NSTEPS (T_IN + T_OUT - 1)   // 511 total timesteps

// fp16-packed weight layout offsets inside d_ws (units: _Float16 elements).
// Layout per matrix: dst[((k>>3)*N + j)*8 + (k&7)]  -> 16B per (k8, column j)
#define OFF_W0  0u         // 128*768
#define OFF_U0  98304u     // 256*768
#define OFF_W1  294912u
#define OFF_U1  491520u
#define OFF_W2  688128u
#define OFF_U2  884736u
#define OFF_WD  1081344u   // 256*128
#define WS_NEED_BYTES (2228224u)   // 1114112 halves * 2B

typedef _Float16 h2 __attribute__((ext_vector_type(2)));

__device__ __forceinline__ float sigmoidf_(float x) {
    return 1.0f / (1.0f + __expf(-x));
}

__device__ __forceinline__ float fdot2_(unsigned x, unsigned w, float acc) {
#if __has_builtin(__builtin_amdgcn_fdot2)
    return __builtin_amdgcn_fdot2(__builtin_bit_cast(h2, x),
                                  __builtin_bit_cast(h2, w), acc, false);
#else
    h2 xv = __builtin_bit_cast(h2, x), wv = __builtin_bit_cast(h2, w);
    acc = fmaf((float)xv[0], (float)wv[0], acc);
    return fmaf((float)xv[1], (float)wv[1], acc);
#endif
}

__device__ __forceinline__ unsigned packh2(float a, float b) {
    h2 v; v[0] = (_Float16)a; v[1] = (_Float16)b;
    return __builtin_bit_cast(unsigned, v);
}

// ---- repack: fp32 [K][N] -> fp16 [(K/8)][N][8] ----
__global__ void repack_k8(const float* __restrict__ src, _Float16* __restrict__ dst,
                          int K, int N) {
    int idx = blockIdx.x * 256 + threadIdx.x;
    if (idx >= K * N) return;
    int k = idx / N, j = idx - k * N;
    dst[((size_t)(k >> 3) * N + j) * 8 + (k & 7)] = (_Float16)src[idx];
}

// ---- main fp16 kernel: one WG per batch element, 768 threads ----
__global__ __launch_bounds__(G3) void gru_ar_fp16(
    const float* __restrict__ inputs,  // [B, T_IN, D]
    const float* __restrict__ noise,   // [B, T_IN, D]
    const float* __restrict__ h_init,  // [3, U]
    const float* __restrict__ b0,      // [2, 3U]
    const float* __restrict__ b1,
    const float* __restrict__ b2,
    const float* __restrict__ bd,      // [D]
    const _Float16* __restrict__ wsh,  // packed weights
    float* __restrict__ out)           // [B, T_OUT, D]
{
    const int b = blockIdx.x;
    const int j = threadIdx.x;

    __shared__ unsigned s_xh[UNITS / 2];     // packed half2 of current layer input
    __shared__ unsigned s_hh[3][UNITS / 2];  // packed half2 of states
    __shared__ float s_gz[UNITS], s_gr[UNITS], s_gxn[UNITS], s_ghn[UNITS];

    const uint4* Wp[3] = { (const uint4*)(wsh + OFF_W0),
                           (const uint4*)(wsh + OFF_W1),
                           (const uint4*)(wsh + OFF_W2) };
    const uint4* Up[3] = { (const uint4*)(wsh + OFF_U0),
                           (const uint4*)(wsh + OFF_U1),
                           (const uint4*)(wsh + OFF_U2) };
    const uint4* Wdp = (const uint4*)(wsh + OFF_WD);

    // hoist biases into registers (constant across steps)
    const float* bs[3] = { b0, b1, b2 };
    float bx[3], bh[3];
    #pragma unroll
    for (int l = 0; l < 3; ++l) { bx[l] = bs[l][j]; bh[l] = bs[l][G3 + j]; }
    const float bdj = (j < DIM) ? bd[j] : 0.f;

    float hreg[3] = {0.f, 0.f, 0.f};  // thread j<256 owns h[l][j]
    float xreg = 0.f;                 // layer-input value for unit j (residual chain)
    float predreg = 0.f;              // thread j<128 owns pred[j]

    if (j < UNITS) {
        #pragma unroll
        for (int l = 0; l < 3; ++l) hreg[l] = h_init[l * UNITS + j];
    }
    if (j < UNITS / 2) {
        #pragma unroll
        for (int l = 0; l < 3; ++l)
            s_hh[l][j] = packh2(h_init[l * UNITS + 2 * j], h_init[l * UNITS + 2 * j + 1]);
    }
    __syncthreads();

    for (int t = 0; t < NSTEPS; ++t) {
        // ---- produce packed layer-0 input in s_xh[0 .. D/2) ----
        if (t < T_IN) {
            if (j < DIM / 2) {
                const float2* ip = (const float2*)(inputs + ((size_t)b * T_IN + t) * DIM) + j;
                const float2* np = (const float2*)(noise  + ((size_t)b * T_IN + t) * DIM) + j;
                float2 a = *ip, n = *np;
                s_xh[j] = packh2(a.x + n.x, a.y + n.y);
            }
        } else {
            if (j < DIM) {
                float p1 = __shfl_xor(predreg, 1);
                if (!(j & 1)) s_xh[j >> 1] = packh2(predreg, p1);
            }
        }
        __syncthreads();

        // ---- 3 GRU cells ----
        #pragma unroll
        for (int l = 0; l < 3; ++l) {
            const int K8x = (l == 0) ? (DIM / 8) : (UNITS / 8);
            const uint4* wp = Wp[l] + j;
            const uint4* up = Up[l] + j;
            float a0 = 0.f, a1 = 0.f, c0 = 0.f, c1 = 0.f;
            #pragma unroll 4
            for (int k8 = 0; k8 < K8x; ++k8) {
                uint4 w = wp[(size_t)k8 * G3];
                a0 = fdot2_(s_xh[4 * k8 + 0], w.x, a0);
                a0 = fdot2_(s_xh[4 * k8 + 1], w.y, a0);
                a1 = fdot2_(s_xh[4 * k8 + 2], w.z, a1);
                a1 = fdot2_(s_xh[4 * k8 + 3], w.w, a1);
            }
            #pragma unroll 4
            for (int k8 = 0; k8 < UNITS / 8; ++k8) {
                uint4 u = up[(size_t)k8 * G3];
                c0 = fdot2_(s_hh[l][4 * k8 + 0], u.x, c0);
                c0 = fdot2_(s_hh[l][4 * k8 + 1], u.y, c0);
                c1 = fdot2_(s_hh[l][4 * k8 + 2], u.z, c1);
                c1 = fdot2_(s_hh[l][4 * k8 + 3], u.w, c1);
            }
            const float gx = bx[l] + a0 + a1;
            const float gh = bh[l] + c0 + c1;
            if (j < UNITS)            s_gz[j] = gx + gh;
            else if (j < 2 * UNITS)   s_gr[j - UNITS] = gx + gh;
            else { s_gxn[j - 2 * UNITS] = gx; s_ghn[j - 2 * UNITS] = gh; }
            __syncthreads();

            if (j < UNITS) {
                const float z = sigmoidf_(s_gz[j]);
                const float r = sigmoidf_(s_gr[j]);
                const float n = tanhf(s_gxn[j] + r * s_ghn[j]);
                const float hnew = z * hreg[l] + (1.f - z) * n;
                hreg[l] = hnew;
                xreg = (l == 0) ? hnew : (hnew + xreg);
                // pack pairs via lane pairing (j, j^1 in same wave)
                const float h1 = __shfl_xor(hnew, 1);
                const float x1 = __shfl_xor(xreg, 1);
                if (!(j & 1)) {
                    s_hh[l][j >> 1] = packh2(hnew, h1);
                    s_xh[j >> 1]    = packh2(xreg, x1);
                }
            }
            __syncthreads();
        }

        // ---- dense readout (only once AR output is needed) ----
        if (t >= T_IN - 1) {
            if (j < DIM) {
                const uint4* wd = Wdp + j;
                float a0 = 0.f, a1 = 0.f;
                #pragma unroll 4
                for (int k8 = 0; k8 < UNITS / 8; ++k8) {
                    uint4 w = wd[(size_t)k8 * DIM];
                    a0 = fdot2_(s_xh[4 * k8 + 0], w.x, a0);
                    a0 = fdot2_(s_xh[4 * k8 + 1], w.y, a0);
                    a1 = fdot2_(s_xh[4 * k8 + 2], w.z, a1);
                    a1 = fdot2_(s_xh[4 * k8 + 3], w.w, a1);
                }
                predreg = bdj + a0 + a1;
                out[((size_t)b * T_OUT + (t - (T_IN - 1))) * DIM + j] = predreg;
            }
            __syncthreads();  // protect s_xh against next step's rewrite
        }
    }
}

// ---- fallback: verified round-1 fp32 kernel (used only if ws too small) ----
__global__ __launch_bounds__(G3) void gru_ar_fp32(
    const float* __restrict__ inputs, const float* __restrict__ noise,
    const float* __restrict__ h_init,
    const float* __restrict__ W0, const float* __restrict__ U0, const float* __restrict__ b0,
    const float* __restrict__ W1, const float* __restrict__ U1, const float* __restrict__ b1,
    const float* __restrict__ W2, const float* __restrict__ U2, const float* __restrict__ b2,
    const float* __restrict__ Wd, const float* __restrict__ bd,
    float* __restrict__ out)
{
    const int b = blockIdx.x;
    const int j = threadIdx.x;

    __shared__ float s_x[UNITS];
    __shared__ float s_h[3][UNITS];
    __shared__ float s_gz[UNITS], s_gr[UNITS], s_gxn[UNITS], s_ghn[UNITS];
    __shared__ float s_pred[DIM];

    if (j < UNITS) {
        s_h[0][j] = h_init[0 * UNITS + j];
        s_h[1][j] = h_init[1 * UNITS + j];
        s_h[2][j] = h_init[2 * UNITS + j];
    }
    __syncthreads();

    const float* Ws[3]  = {W0, W1, W2};
    const float* Us[3]  = {U0, U1, U2};
    const float* bss[3] = {b0, b1, b2};

    for (int t = 0; t < NSTEPS; ++t) {
        if (j < DIM) {
            if (t < T_IN) {
                const int idx = (b * T_IN + t) * DIM + j;
                s_x[j] = inputs[idx] + noise[idx];
            } else {
                s_x[j] = s_pred[j];
            }
        }
        __syncthreads();

        #pragma unroll
        for (int l = 0; l < 3; ++l) {
            const int K = (l == 0) ? DIM : UNITS;
            const float* __restrict__ W    = Ws[l];
            const float* __restrict__ Urec = Us[l];
            const float* __restrict__ bias = bss[l];

            float gx = bias[j];
            #pragma unroll 4
            for (int k = 0; k < K; ++k) gx = fmaf(s_x[k], W[k * G3 + j], gx);
            float gh = bias[G3 + j];
            #pragma unroll 4
            for (int k = 0; k < UNITS; ++k) gh = fmaf(s_h[l][k], Urec[k * G3 + j], gh);

            if (j < UNITS)            s_gz[j] = gx + gh;
            else if (j < 2 * UNITS)   s_gr[j - UNITS] = gx + gh;
            else { s_gxn[j - 2 * UNITS] = gx; s_ghn[j - 2 * UNITS] = gh; }
            __syncthreads();

            if (j < UNITS) {
                const float z = sigmoidf_(s_gz[j]);
                const float r = sigmoidf_(s_gr[j]);
                const float n = tanhf(s_gxn[j] + r * s_ghn[j]);
                const float h_old = s_h[l][j];
                const float h_new = z * h_old + (1.0f - z) * n;
                s_h[l][j] = h_new;
                s_x[j] = (l == 0) ? h_new : (h_new + s_x[j]);
            }
            __syncthreads();
        }

        if (t >= T_IN - 1) {
            if (j < DIM) {
                float p = bd[j];
                #pragma unroll 4
                for (int k = 0; k < UNITS; ++k) p = fmaf(s_x[k], Wd[k * DIM + j], p);
                s_pred[j] = p;
                out[(b * T_OUT + (t - (T_IN - 1))) * DIM + j] = p;
            }
            __syncthreads();
        }
    }
}

extern "C" void kernel_launch(void* const* d_in, const int* in_sizes, int n_in,
                              void* d_out, int out_size, void* d_ws, size_t ws_size,
                              hipStream_t stream) {
    const float* inputs = (const float*)d_in[0];
    const float* noise  = (const float*)d_in[1];
    const float* h_init = (const float*)d_in[2];
    const float* W0 = (const float*)d_in[3];
    const float* U0 = (const float*)d_in[4];
    const float* b0 = (const float*)d_in[5];
    const float* W1 = (const float*)d_in[6];
    const float* U1 = (const float*)d_in[7];
    const float* b1 = (const float*)d_in[8];
    const float* W2 = (const float*)d_in[9];
    const float* U2 = (const float*)d_in[10];
    const float* b2 = (const float*)d_in[11];
    const float* Wd = (const float*)d_in[12];
    const float* bd = (const float*)d_in[13];
    float* out = (float*)d_out;

    if (ws_size >= (size_t)WS_NEED_BYTES) {
        _Float16* wsh = (_Float16*)d_ws;
        // repack all weights every call (deterministic)
        auto rp = [&](const float* s, unsigned off, int K, int N) {
            int n = K * N;
            repack_k8<<<(n + 255) / 256, 256, 0, stream>>>(s, wsh + off, K, N);
        };
        rp(W0, OFF_W0, 128, 768);
        rp(U0, OFF_U0, 256, 768);
        rp(W1, OFF_W1, 256, 768);
        rp(U1, OFF_U1, 256, 768);
        rp(W2, OFF_W2, 256, 768);
        rp(U2, OFF_U2, 256, 768);
        rp(Wd, OFF_WD, 256, 128);
        gru_ar_fp16<<<BATCH, G3, 0, stream>>>(
            inputs, noise, h_init, b0, b1, b2, bd, wsh, out);
    } else {
        gru_ar_fp32<<<BATCH, G3, 0, stream>>>(
            inputs, noise, h_init, W0, U0, b0, W1, U1, b1, W2, U2, b2, Wd, bd, out);
    }
}